// Round 2
// baseline (74.665 us; speedup 1.0000x reference)
//
#include <hip/hip_runtime.h>
#include <hip/hip_bf16.h>
#include <math.h>

// Problem dims (fixed by reference): B=64, N=32, S=1024, D=128
#define NB 64
#define NTOK 32
#define NS 1024
#define ND 128

typedef __attribute__((ext_vector_type(8))) short short8;  // 8 x bf16
typedef __attribute__((ext_vector_type(4))) float f32x4;

__device__ __forceinline__ unsigned short f2bf(float x) {
    unsigned int u = __builtin_bit_cast(unsigned int, x);
    u += 0x7fffu + ((u >> 16) & 1u);  // round-to-nearest-even
    return (unsigned short)(u >> 16);
}

// Input: [ntiles*16][128] fp32 (row-major). Output: per 16-row tile, MFMA
// A/B fragment layout: [tile][kstep(4)][lane(64)][8] bf16 (2048 bf16/tile).
// Fragment map: lane l holds row (l&15), k = kstep*32 + 8*(l>>4) + j.
// (Any error in the assumed k-permutation cancels: A and B use the same map.)
__global__ __launch_bounds__(256) void convert_frag(const float* __restrict__ in,
                                                    short* __restrict__ out) {
    int tile = blockIdx.x;
    int t = threadIdx.x;          // 256 threads = 4 waves; wave id == kstep
    int ks = t >> 6;
    int l = t & 63;
    const float* src = in + (tile * 16 + (l & 15)) * ND + ks * 32 + 8 * (l >> 4);
    float4 a = *(const float4*)src;
    float4 b = *(const float4*)(src + 4);
    float f[8] = {a.x, a.y, a.z, a.w, b.x, b.y, b.z, b.w};
    short8 r;
#pragma unroll
    for (int j = 0; j < 8; ++j) r[j] = (short)f2bf(f[j]);
    *(short8*)(out + tile * 2048 + t * 8) = r;  // coalesced 16B/lane
}

// Main in-batch maxsim: scores[b][c] = sum_n max_s q[b,n]·d[c,s]
// Grid: (8 bgroups, 64 c). Block: 256 thr = 4 waves, each wave owns 2 b's
// (q fragments in registers). doc[c] staged chunk-wise (64 rows = 16KB) into
// double-buffered LDS via REGISTER staging (plain loads + ds_write_b128):
// only standard vmcnt/lgkmcnt semantics, one barrier per chunk, race-free.
__global__ __launch_bounds__(256, 2) void maxsim_main(const short* __restrict__ qf,
                                                      const short* __restrict__ df,
                                                      float* __restrict__ scores) {
    int bg = blockIdx.x;
    int c = blockIdx.y;
    int t = threadIdx.x;
    int w = t >> 6, l = t & 63;
    int b0 = bg * 8 + w * 2;  // this wave: b0, b0+1

    __shared__ alignas(16) short lds[2][8192];  // 2 x 16KB chunks

    // q fragments: [bb][mtile][kstep], 8 bf16 each (4 VGPR) -> 64 VGPR
    short8 qa[2][2][4];
#pragma unroll
    for (int bb = 0; bb < 2; ++bb)
#pragma unroll
        for (int m = 0; m < 2; ++m)
#pragma unroll
            for (int ks = 0; ks < 4; ++ks)
                qa[bb][m][ks] =
                    *(const short8*)(qf + (((b0 + bb) * 2 + m) * 4 + ks) * 512 + l * 8);

    const short* dbase = df + c * (NS * ND);  // 131072 bf16 per c

    f32x4 vmax[2][2];
#pragma unroll
    for (int bb = 0; bb < 2; ++bb)
#pragma unroll
        for (int m = 0; m < 2; ++m)
#pragma unroll
            for (int r = 0; r < 4; ++r) vmax[bb][m][r] = -INFINITY;
    f32x4 zero = {0.f, 0.f, 0.f, 0.f};

    // prologue: stage chunk 0 (16KB; 64B/thread = 4 x 16B, coalesced)
    {
        short8 st[4];
#pragma unroll
        for (int i = 0; i < 4; ++i)
            st[i] = *(const short8*)(dbase + i * 2048 + t * 8);
#pragma unroll
        for (int i = 0; i < 4; ++i)
            *(short8*)(&lds[0][i * 2048 + t * 8]) = st[i];
    }

    for (int ch = 0; ch < 16; ++ch) {
        int p = ch & 1;
        short8 nx[4];
        if (ch + 1 < 16) {  // issue next chunk's global loads BEFORE the barrier
#pragma unroll
            for (int i = 0; i < 4; ++i)
                nx[i] = *(const short8*)(dbase + (ch + 1) * 8192 + i * 2048 + t * 8);
        }
        __syncthreads();  // buf[p] writes visible; prior reads of buf[p^1] drained
        if (ch + 1 < 16) {
#pragma unroll
            for (int i = 0; i < 4; ++i)
                *(short8*)(&lds[p ^ 1][i * 2048 + t * 8]) = nx[i];
        }
#pragma unroll
        for (int ss = 0; ss < 4; ++ss) {  // 4 s-subtiles of 16 docs
            short8 bf[4];
#pragma unroll
            for (int ks = 0; ks < 4; ++ks)
                bf[ks] = *(const short8*)(&lds[p][((ss * 4 + ks) * 64 + l) * 8]);
#pragma unroll
            for (int bb = 0; bb < 2; ++bb)
#pragma unroll
                for (int m = 0; m < 2; ++m) {
                    f32x4 acc = zero;
#pragma unroll
                    for (int ks = 0; ks < 4; ++ks)
                        acc = __builtin_amdgcn_mfma_f32_16x16x32_bf16(qa[bb][m][ks],
                                                                      bf[ks], acc, 0, 0, 0);
#pragma unroll
                    for (int r = 0; r < 4; ++r)
                        vmax[bb][m][r] = fmaxf(vmax[bb][m][r], acc[r]);
                }
        }
    }

    // C layout: col(=s) = lane&15, row(=n) = (lane>>4)*4 + reg.
    // rowmax: max across the 16 lanes sharing (lane>>4); then sum rows.
#pragma unroll
    for (int bb = 0; bb < 2; ++bb) {
        float rs = 0.f;
#pragma unroll
        for (int m = 0; m < 2; ++m)
#pragma unroll
            for (int r = 0; r < 4; ++r) {
                float v = vmax[bb][m][r];
                v = fmaxf(v, __shfl_xor(v, 1));
                v = fmaxf(v, __shfl_xor(v, 2));
                v = fmaxf(v, __shfl_xor(v, 4));
                v = fmaxf(v, __shfl_xor(v, 8));
                rs += v;  // 4 rows of this lane's quarter-group
            }
        rs += __shfl_xor(rs, 16);  // sum across the 4 row-groups
        rs += __shfl_xor(rs, 32);
        if (l == 0) scores[(b0 + bb) * NB + c] = rs;
    }
}

// neg_scores[b] = sum_n max_s q[b,n]·neg[b,s]. One block per b, 8 waves,
// each wave covers 128 doc rows; fragments read straight from global.
__global__ __launch_bounds__(512) void maxsim_neg(const short* __restrict__ qf,
                                                  const short* __restrict__ nf,
                                                  float* __restrict__ negs) {
    int b = blockIdx.x;
    int t = threadIdx.x;
    int w = t >> 6, l = t & 63;
    __shared__ float red[8][32];

    short8 qa[2][4];
#pragma unroll
    for (int m = 0; m < 2; ++m)
#pragma unroll
        for (int ks = 0; ks < 4; ++ks)
            qa[m][ks] = *(const short8*)(qf + ((b * 2 + m) * 4 + ks) * 512 + l * 8);

    f32x4 vmax[2];
#pragma unroll
    for (int m = 0; m < 2; ++m)
#pragma unroll
        for (int r = 0; r < 4; ++r) vmax[m][r] = -INFINITY;
    f32x4 zero = {0.f, 0.f, 0.f, 0.f};

    for (int st = 0; st < 8; ++st) {
        int tile = b * 64 + w * 8 + st;
        short8 bf[4];
#pragma unroll
        for (int ks = 0; ks < 4; ++ks)
            bf[ks] = *(const short8*)(nf + (tile * 4 + ks) * 512 + l * 8);
#pragma unroll
        for (int m = 0; m < 2; ++m) {
            f32x4 acc = zero;
#pragma unroll
            for (int ks = 0; ks < 4; ++ks)
                acc = __builtin_amdgcn_mfma_f32_16x16x32_bf16(qa[m][ks], bf[ks], acc, 0, 0, 0);
#pragma unroll
            for (int r = 0; r < 4; ++r) vmax[m][r] = fmaxf(vmax[m][r], acc[r]);
        }
    }

#pragma unroll
    for (int m = 0; m < 2; ++m)
#pragma unroll
        for (int r = 0; r < 4; ++r) {
            float v = vmax[m][r];
            v = fmaxf(v, __shfl_xor(v, 1));
            v = fmaxf(v, __shfl_xor(v, 2));
            v = fmaxf(v, __shfl_xor(v, 4));
            v = fmaxf(v, __shfl_xor(v, 8));
            if ((l & 15) == 0) red[w][m * 16 + (l >> 4) * 4 + r] = v;  // partial rowmax
        }
    __syncthreads();
    if (t < 64) {
        float s = 0.f;
        if (t < 32) {
            float rm = -INFINITY;
#pragma unroll
            for (int w2 = 0; w2 < 8; ++w2) rm = fmaxf(rm, red[w2][t]);
            s = rm;
        }
        s += __shfl_xor(s, 1);
        s += __shfl_xor(s, 2);
        s += __shfl_xor(s, 4);
        s += __shfl_xor(s, 8);
        s += __shfl_xor(s, 16);
        s += __shfl_xor(s, 32);
        if (t == 0) negs[b] = s;
    }
}

// Final loss: softplus((neg-pos)/T).mean() + CE(log_softmax(scores/T), labels), /2
__global__ void reduce_loss(const float* __restrict__ scores, const float* __restrict__ negs,
                            const int* __restrict__ offp, float* __restrict__ out) {
    int b = threadIdx.x;  // 64 threads = 1 wave
    const float invT = 50.0f;
    float mx = -INFINITY;
    for (int c = 0; c < NB; ++c) mx = fmaxf(mx, scores[b * NB + c]);
    float se = 0.f;
    for (int c = 0; c < NB; ++c) se += expf((scores[b * NB + c] - mx) * invT);
    float lse = mx * invT + logf(se);
    int label = offp[0] + b;
    label = label < 0 ? 0 : (label > 63 ? 63 : label);
    float ce = lse - scores[b * NB + label] * invT;
    float pos = scores[b * NB + b];
    float x = (negs[b] - pos) * invT;
    float sp = fmaxf(x, 0.f) + log1pf(expf(-fabsf(x)));
    float tot = sp + ce;
    tot += __shfl_xor(tot, 1);
    tot += __shfl_xor(tot, 2);
    tot += __shfl_xor(tot, 4);
    tot += __shfl_xor(tot, 8);
    tot += __shfl_xor(tot, 16);
    tot += __shfl_xor(tot, 32);
    if (b == 0) out[0] = tot * (0.5f / 64.f);
}

extern "C" void kernel_launch(void* const* d_in, const int* in_sizes, int n_in,
                              void* d_out, int out_size, void* d_ws, size_t ws_size,
                              hipStream_t stream) {
    const float* q = (const float*)d_in[0];
    const float* dc = (const float*)d_in[1];
    const float* ng = (const float*)d_in[2];
    const int* offp = (const int*)d_in[3];
    float* out = (float*)d_out;

    // ws layout (bytes): qf 512KB | df 16MB | nf 16MB | scores 16KB | negs 256B
    char* ws = (char*)d_ws;
    short* qf = (short*)(ws);
    short* df = (short*)(ws + (1u << 19));
    short* nf = (short*)(ws + (1u << 19) + (1u << 24));
    float* scores = (float*)(ws + (1u << 19) + (1u << 25));
    float* negs = (float*)(ws + (1u << 19) + (1u << 25) + (1u << 14));
    if (ws_size < ((1u << 19) + (1u << 25) + (1u << 14) + 256)) return;

    convert_frag<<<(NB * NTOK) / 16, 256, 0, stream>>>(q, qf);       // 128 tiles
    convert_frag<<<(NB * NS) / 16, 256, 0, stream>>>(dc, df);        // 4096 tiles
    convert_frag<<<(NB * NS) / 16, 256, 0, stream>>>(ng, nf);        // 4096 tiles
    maxsim_main<<<dim3(8, 64), 256, 0, stream>>>(qf, df, scores);
    maxsim_neg<<<NB, 512, 0, stream>>>(qf, nf, negs);
    reduce_loss<<<1, 64, 0, stream>>>(scores, negs, offp, out);
}

// Round 3
// 72.466 us; speedup vs baseline: 1.0303x; 1.0303x over previous
//
#include <hip/hip_runtime.h>
#include <hip/hip_bf16.h>
#include <math.h>

// Problem dims (fixed by reference): B=64, N=32, S=1024, D=128
#define NB 64
#define NTOK 32
#define NS 1024
#define ND 128

typedef __attribute__((ext_vector_type(8))) short short8;  // 8 x bf16
typedef __attribute__((ext_vector_type(4))) float f32x4;

__device__ __forceinline__ unsigned short f2bf(float x) {
    unsigned int u = __builtin_bit_cast(unsigned int, x);
    u += 0x7fffu + ((u >> 16) & 1u);  // round-to-nearest-even
    return (unsigned short)(u >> 16);
}

// Fused convert of all three tensors. Tile = 16 rows x 128 cols fp32 ->
// MFMA fragment layout [tile][kstep(4)][lane(64)][8] bf16.
// Map: lane l holds row (l&15), k = kstep*32 + 8*(l>>4) + j. A and B use the
// identical map, so any k-permutation error cancels in the dot product.
__global__ __launch_bounds__(256) void convert_all(const float* __restrict__ q,
                                                   const float* __restrict__ dc,
                                                   const float* __restrict__ ng,
                                                   short* __restrict__ qf,
                                                   short* __restrict__ df,
                                                   short* __restrict__ nf) {
    int tile = blockIdx.x;  // [0,128) q | [128,4224) doc | [4224,8320) neg
    const float* in;
    short* out;
    int rel;
    if (tile < 128)       { in = q;  out = qf; rel = tile; }
    else if (tile < 4224) { in = dc; out = df; rel = tile - 128; }
    else                  { in = ng; out = nf; rel = tile - 4224; }
    int t = threadIdx.x;  // 256 threads = 4 waves; wave id == kstep
    int ks = t >> 6;
    int l = t & 63;
    const float* src = in + (rel * 16 + (l & 15)) * ND + ks * 32 + 8 * (l >> 4);
    float4 a = *(const float4*)src;
    float4 b = *(const float4*)(src + 4);
    float f[8] = {a.x, a.y, a.z, a.w, b.x, b.y, b.z, b.w};
    short8 r;
#pragma unroll
    for (int j = 0; j < 8; ++j) r[j] = (short)f2bf(f[j]);
    *(short8*)(out + rel * 2048 + t * 8) = r;  // coalesced 16B/lane
}

// Main in-batch maxsim + distributed neg-maxsim partials.
// Grid (8 bg, 64 c); block 256 thr = 4 waves, each wave owns 2 b's.
//  - main: scores[b][c] = sum_n max_s q[b,n]·d[c,s]; doc[c] staged in
//    double-buffered LDS via register staging, software-pipelined: loads for
//    chunk X issue a full compute phase before their ds_write.
//  - neg: this block also computes rowmax over s-chunk c of q[b]·neg[b] for
//    its 8 b's (1 tile/b, +1.6% MFMA) -> neg_part[c][b][n].
__global__ __launch_bounds__(256, 2) void maxsim_main(const short* __restrict__ qf,
                                                      const short* __restrict__ df,
                                                      const short* __restrict__ nf,
                                                      float* __restrict__ scores,
                                                      float* __restrict__ neg_part) {
    int bg = blockIdx.x;
    int c = blockIdx.y;
    int t = threadIdx.x;
    int w = t >> 6, l = t & 63;
    int b0 = bg * 8 + w * 2;  // this wave: b0, b0+1

    __shared__ alignas(16) short lds[2][8192];  // 2 x 16KB chunks
    const short* dbase = df + c * (NS * ND);    // 131072 bf16 per c
    f32x4 zero = {0.f, 0.f, 0.f, 0.f};

    // issue chunk-0 loads immediately (latency hidden under q-load + neg work)
    short8 ra[4], rb[4];
#pragma unroll
    for (int i = 0; i < 4; ++i)
        ra[i] = *(const short8*)(dbase + i * 2048 + t * 8);

    // q fragments: [bb][mtile][kstep] -> 64 VGPR
    short8 qa[2][2][4];
#pragma unroll
    for (int bb = 0; bb < 2; ++bb)
#pragma unroll
        for (int m = 0; m < 2; ++m)
#pragma unroll
            for (int ks = 0; ks < 4; ++ks)
                qa[bb][m][ks] =
                    *(const short8*)(qf + (((b0 + bb) * 2 + m) * 4 + ks) * 512 + l * 8);

    // ---- fused neg partial: tile (b, s-chunk c) of q[b]·neg[b] ----
#pragma unroll
    for (int bb = 0; bb < 2; ++bb) {
        const short* nt_ = nf + (((b0 + bb) * 64 + c) * 4) * 512;
        short8 nb[4];
#pragma unroll
        for (int ks = 0; ks < 4; ++ks)
            nb[ks] = *(const short8*)(nt_ + ks * 512 + l * 8);
#pragma unroll
        for (int m = 0; m < 2; ++m) {
            f32x4 acc = zero;
#pragma unroll
            for (int ks = 0; ks < 4; ++ks)
                acc = __builtin_amdgcn_mfma_f32_16x16x32_bf16(qa[bb][m][ks], nb[ks], acc, 0, 0, 0);
#pragma unroll
            for (int r = 0; r < 4; ++r) {  // rowmax over s (lanes sharing l>>4)
                float v = acc[r];
                v = fmaxf(v, __shfl_xor(v, 1));
                v = fmaxf(v, __shfl_xor(v, 2));
                v = fmaxf(v, __shfl_xor(v, 4));
                v = fmaxf(v, __shfl_xor(v, 8));
                if ((l & 15) == 0)
                    neg_part[(c * 64 + (b0 + bb)) * 32 + m * 16 + (l >> 4) * 4 + r] = v;
            }
        }
    }

    // write chunk0 (vmcnt wait on ra covered by neg work above), issue chunk1
#pragma unroll
    for (int i = 0; i < 4; ++i)
        *(short8*)(&lds[0][i * 2048 + t * 8]) = ra[i];
#pragma unroll
    for (int i = 0; i < 4; ++i)
        rb[i] = *(const short8*)(dbase + 8192 + i * 2048 + t * 8);
    __syncthreads();  // publish buf0

    f32x4 vmax[2][2];
#pragma unroll
    for (int bb = 0; bb < 2; ++bb)
#pragma unroll
        for (int m = 0; m < 2; ++m)
#pragma unroll
            for (int r = 0; r < 4; ++r) vmax[bb][m][r] = -INFINITY;

#define COMPUTE(PP)                                                                     \
    _Pragma("unroll") for (int ss = 0; ss < 4; ++ss) {                                  \
        short8 bf[4];                                                                   \
        _Pragma("unroll") for (int ks = 0; ks < 4; ++ks)                                \
            bf[ks] = *(const short8*)(&lds[PP][((ss * 4 + ks) * 64 + l) * 8]);          \
        _Pragma("unroll") for (int bb = 0; bb < 2; ++bb)                                \
            _Pragma("unroll") for (int m = 0; m < 2; ++m) {                             \
                f32x4 acc = zero;                                                       \
                _Pragma("unroll") for (int ks = 0; ks < 4; ++ks)                        \
                    acc = __builtin_amdgcn_mfma_f32_16x16x32_bf16(qa[bb][m][ks],        \
                                                                  bf[ks], acc, 0, 0, 0);\
                _Pragma("unroll") for (int r = 0; r < 4; ++r)                           \
                    vmax[bb][m][r] = fmaxf(vmax[bb][m][r], acc[r]);                     \
            }                                                                           \
    }

    // Invariant at loop top: buf0 = chunk ch (published), rb = chunk ch+1 (in flight)
    for (int it = 0; it < 8; ++it) {
        int ch = it * 2;
        if (ch + 2 < 16) {  // issue loads 2 chunks ahead -> consumed after 2 computes
#pragma unroll
            for (int i = 0; i < 4; ++i)
                ra[i] = *(const short8*)(dbase + (ch + 2) * 8192 + i * 2048 + t * 8);
        }
        COMPUTE(0);  // chunk ch
#pragma unroll
        for (int i = 0; i < 4; ++i)  // rb's vmcnt satisfied ~1 compute phase ago
            *(short8*)(&lds[1][i * 2048 + t * 8]) = rb[i];
        __syncthreads();  // publish buf1; all waves done with buf0
        if (ch + 3 < 16) {
#pragma unroll
            for (int i = 0; i < 4; ++i)
                rb[i] = *(const short8*)(dbase + (ch + 3) * 8192 + i * 2048 + t * 8);
        }
        COMPUTE(1);  // chunk ch+1
        if (ch + 2 < 16) {
#pragma unroll
            for (int i = 0; i < 4; ++i)
                *(short8*)(&lds[0][i * 2048 + t * 8]) = ra[i];
            __syncthreads();  // publish buf0 for next iter (uniform branch)
        }
    }
#undef COMPUTE

    // C layout: col(=s) = lane&15, row(=n) = (lane>>4)*4 + reg.
#pragma unroll
    for (int bb = 0; bb < 2; ++bb) {
        float rs = 0.f;
#pragma unroll
        for (int m = 0; m < 2; ++m)
#pragma unroll
            for (int r = 0; r < 4; ++r) {
                float v = vmax[bb][m][r];
                v = fmaxf(v, __shfl_xor(v, 1));
                v = fmaxf(v, __shfl_xor(v, 2));
                v = fmaxf(v, __shfl_xor(v, 4));
                v = fmaxf(v, __shfl_xor(v, 8));
                rs += v;
            }
        rs += __shfl_xor(rs, 16);
        rs += __shfl_xor(rs, 32);
        if (l == 0) scores[(b0 + bb) * NB + c] = rs;
    }
}

// Final: reduce neg partials over c, then softplus + CE, mean, /2.
__global__ __launch_bounds__(256) void reduce_loss(const float* __restrict__ scores,
                                                   const float* __restrict__ neg_part,
                                                   const int* __restrict__ offp,
                                                   float* __restrict__ out) {
    __shared__ float negsum[64][4];
    __shared__ float bloss[64];
    int t = threadIdx.x;
    {
        int b = t >> 2, q4 = t & 3;  // thread covers n in [q4*8, q4*8+8) of b
        float mx[8];
#pragma unroll
        for (int j = 0; j < 8; ++j) mx[j] = -INFINITY;
        for (int c = 0; c < 64; ++c) {
            const float4* p = (const float4*)(neg_part + ((c * 64 + b) * 32 + q4 * 8));
            float4 a = p[0], bq = p[1];
            mx[0] = fmaxf(mx[0], a.x);  mx[1] = fmaxf(mx[1], a.y);
            mx[2] = fmaxf(mx[2], a.z);  mx[3] = fmaxf(mx[3], a.w);
            mx[4] = fmaxf(mx[4], bq.x); mx[5] = fmaxf(mx[5], bq.y);
            mx[6] = fmaxf(mx[6], bq.z); mx[7] = fmaxf(mx[7], bq.w);
        }
        float s = 0.f;
#pragma unroll
        for (int j = 0; j < 8; ++j) s += mx[j];
        negsum[b][q4] = s;
    }
    __syncthreads();
    if (t < 64) {
        int b = t;
        float negs = negsum[b][0] + negsum[b][1] + negsum[b][2] + negsum[b][3];
        const float invT = 50.0f;
        float mxs = -INFINITY;
        for (int c = 0; c < NB; ++c) mxs = fmaxf(mxs, scores[b * NB + c]);
        float se = 0.f;
        for (int c = 0; c < NB; ++c) se += expf((scores[b * NB + c] - mxs) * invT);
        float lse = mxs * invT + logf(se);
        int label = offp[0] + b;
        label = label < 0 ? 0 : (label > 63 ? 63 : label);
        float ce = lse - scores[b * NB + label] * invT;
        float pos = scores[b * NB + b];
        float x = (negs - pos) * invT;
        float sp = fmaxf(x, 0.f) + log1pf(expf(-fabsf(x)));
        bloss[b] = sp + ce;
    }
    __syncthreads();
    if (t < 64) {
        float v = bloss[t];
        v += __shfl_xor(v, 1);
        v += __shfl_xor(v, 2);
        v += __shfl_xor(v, 4);
        v += __shfl_xor(v, 8);
        v += __shfl_xor(v, 16);
        v += __shfl_xor(v, 32);
        if (t == 0) out[0] = v * (0.5f / 64.f);
    }
}

extern "C" void kernel_launch(void* const* d_in, const int* in_sizes, int n_in,
                              void* d_out, int out_size, void* d_ws, size_t ws_size,
                              hipStream_t stream) {
    const float* q = (const float*)d_in[0];
    const float* dc = (const float*)d_in[1];
    const float* ng = (const float*)d_in[2];
    const int* offp = (const int*)d_in[3];
    float* out = (float*)d_out;

    // ws layout: qf 512KB | df 16MB | nf 16MB | scores 16KB | neg_part 512KB
    char* ws = (char*)d_ws;
    short* qf = (short*)(ws);
    short* df = (short*)(ws + 0x80000);
    short* nf = (short*)(ws + 0x1080000);
    float* scores = (float*)(ws + 0x2080000);
    float* neg_part = (float*)(ws + 0x2084000);
    if (ws_size < 0x2104000) return;

    convert_all<<<8320, 256, 0, stream>>>(q, dc, ng, qf, df, nf);
    maxsim_main<<<dim3(8, 64), 256, 0, stream>>>(qf, df, nf, scores, neg_part);
    reduce_loss<<<1, 256, 0, stream>>>(scores, neg_part, offp, out);
}